// Round 2
// baseline (1291.727 us; speedup 1.0000x reference)
//
#include <hip/hip_runtime.h>
#include <stdint.h>

// GCN 2-layer: out = drop(relu(A_hat * (drop(relu((A_hat*X)*W1+b1)) * W2) + b2))
// A_hat applied at 256 channels in both layers (aggregate-first / multiply-first).
// Dropout: JAX threefry2x32 in PARTITIONABLE mode (default since jax 0.4.30):
//   random_bits(32): elem j -> threefry(key, (0, j)), bits = out0 ^ out1
//   split(key): key i  -> threefry(key, (0, i)), new key = (out0, out1)

#define C_IN 256
#define C_HID 512
#define C_OUT 256

// ---------------- Threefry-2x32 (matches JAX) ----------------
__host__ __device__ __forceinline__ void tf_rounds(unsigned& x0, unsigned& x1,
                                                   unsigned k0, unsigned k1) {
  unsigned k2 = k0 ^ k1 ^ 0x1BD11BDAu;
#define ROT(r) { x0 += x1; x1 = (x1 << r) | (x1 >> (32 - r)); x1 ^= x0; }
  x0 += k0; x1 += k1;
  ROT(13) ROT(15) ROT(26) ROT(6)
  x0 += k1; x1 += k2 + 1u;
  ROT(17) ROT(29) ROT(16) ROT(24)
  x0 += k2; x1 += k0 + 2u;
  ROT(13) ROT(15) ROT(26) ROT(6)
  x0 += k0; x1 += k1 + 3u;
  ROT(17) ROT(29) ROT(16) ROT(24)
  x0 += k1; x1 += k2 + 4u;
  ROT(13) ROT(15) ROT(26) ROT(6)
  x0 += k2; x1 += k0 + 5u;
#undef ROT
}

// partitionable-mode dropout scale for flat element j (size < 2^32 so hi=0)
__device__ __forceinline__ float drop_scale(unsigned j, unsigned k0, unsigned k1) {
  unsigned x0 = 0u, x1 = j;
  tf_rounds(x0, x1, k0, k1);
  unsigned bits = x0 ^ x1;
  float u = __uint_as_float((bits >> 9) | 0x3f800000u) - 1.0f;
  return (u < 0.5f) ? 2.0f : 0.0f;  // keep-prob 0.5, scale 1/(1-p)=2
}

// ---------------- edge-index canonicalization ----------------
// If the harness kept int64 edges, every odd 32-bit word (high half) is 0.
__global__ __launch_bounds__(256) void k_detect(const unsigned* __restrict__ raw,
                                                unsigned* flag, int nwords) {
  __shared__ unsigned sh[256];
  unsigned acc = 0;
  for (int i = 1 + 2 * (int)threadIdx.x; i < nwords; i += 512) acc |= raw[i];
  sh[threadIdx.x] = acc;
  __syncthreads();
  for (int s = 128; s > 0; s >>= 1) {
    if ((int)threadIdx.x < s) sh[threadIdx.x] |= sh[threadIdx.x + s];
    __syncthreads();
  }
  if (threadIdx.x == 0) *flag = (sh[0] == 0u) ? 1u : 0u;  // 1 => int64
}

__global__ __launch_bounds__(256) void k_convert(const void* __restrict__ raw,
                                                 const unsigned* __restrict__ flag,
                                                 int* __restrict__ eic, int total) {
  int i = blockIdx.x * 256 + threadIdx.x;
  if (i >= total) return;
  if (*flag) eic[i] = (int)((const long long*)raw)[i];
  else       eic[i] = ((const int*)raw)[i];
}

// ---------------- degree / dinv ----------------
__global__ __launch_bounds__(256) void k_deg_init(float* deg, int n) {
  int i = blockIdx.x * 256 + threadIdx.x;
  if (i < n) deg[i] = 1.0f;  // self-loop
}
__global__ __launch_bounds__(256) void k_deg_count(const int* __restrict__ eic,
                                                   float* deg, int E) {
  int e = blockIdx.x * 256 + threadIdx.x;
  if (e < E) unsafeAtomicAdd(&deg[eic[E + e]], 1.0f);
}
__global__ __launch_bounds__(256) void k_rsqrt(float* deg, int n) {
  int i = blockIdx.x * 256 + threadIdx.x;
  if (i < n) deg[i] = 1.0f / sqrtf(deg[i]);
}

// ---------------- aggregation (C=256 both layers) ----------------
// self-loop term initializes the accumulator: out[i] = x[i] * dinv[i]^2
__global__ __launch_bounds__(256) void k_self_init(const float* __restrict__ x,
                                                   const float* __restrict__ dinv,
                                                   float* __restrict__ out, int n) {
  int t = blockIdx.x * 256 + threadIdx.x;   // float4 index; 64 per node
  int node = t >> 6;
  if (node >= n) return;
  float di = dinv[node];
  float s = di * di;
  float4 v = ((const float4*)x)[t];
  ((float4*)out)[t] = make_float4(v.x * s, v.y * s, v.z * s, v.w * s);
}

// one wave per edge, lane holds float4 (64*16B = 256 floats)
__global__ __launch_bounds__(256) void k_edge_agg(const int* __restrict__ eic,
                                                  const float* __restrict__ dinv,
                                                  const float* __restrict__ x,
                                                  float* __restrict__ out, int E) {
  int w = (int)((blockIdx.x * 256 + threadIdx.x) >> 6);
  int lane = threadIdx.x & 63;
  if (w >= E) return;
  int s = eic[w], d = eic[E + w];
  float nrm = dinv[s] * dinv[d];
  float4 v = ((const float4*)(x + (size_t)s * 256))[lane];
  float* o = out + (size_t)d * 256 + lane * 4;
  unsafeAtomicAdd(o + 0, v.x * nrm);
  unsafeAtomicAdd(o + 1, v.y * nrm);
  unsafeAtomicAdd(o + 2, v.z * nrm);
  unsafeAtomicAdd(o + 3, v.w * nrm);
}

// ---------------- GEMM: C[M,N] = A[M,K] @ B[K,N], optional bias+relu+dropout ----
template <int EPI>
__global__ __launch_bounds__(256) void k_gemm(const float* __restrict__ A,
                                              const float* __restrict__ B,
                                              const float* __restrict__ bias,
                                              float* __restrict__ C,
                                              int M, int N, int K,
                                              unsigned dk0, unsigned dk1) {
  __shared__ float As[16][68];  // [k][row], +4 pad keeps 16B align, kills 16-way conflict
  __shared__ float Bs[16][64];  // [k][col]
  const int t = threadIdx.x;
  const int tx = t & 15, ty = t >> 4;
  const int row0 = blockIdx.y * 64, col0 = blockIdx.x * 64;
  float acc[4][4] = {};

  for (int kt = 0; kt < K; kt += 16) {
#pragma unroll
    for (int p = 0; p < 4; ++p) {           // A tile: 64 rows x 16 k
      int r = (t >> 4) + p * 16;
      int k = t & 15;
      int gr = row0 + r;
      As[k][r] = (gr < M) ? A[(size_t)gr * K + kt + k] : 0.0f;
    }
#pragma unroll
    for (int p = 0; p < 4; ++p) {           // B tile: 16 k x 64 cols
      int kr = (t >> 6) + p * 4;
      int c = t & 63;
      Bs[kr][c] = B[(size_t)(kt + kr) * N + col0 + c];
    }
    __syncthreads();
#pragma unroll
    for (int kk = 0; kk < 16; ++kk) {
      float4 av = *(const float4*)&As[kk][ty * 4];
      float4 bv = *(const float4*)&Bs[kk][tx * 4];
      float a[4] = {av.x, av.y, av.z, av.w};
      float b[4] = {bv.x, bv.y, bv.z, bv.w};
#pragma unroll
      for (int i = 0; i < 4; ++i)
#pragma unroll
        for (int j = 0; j < 4; ++j)
          acc[i][j] = fmaf(a[i], b[j], acc[i][j]);
    }
    __syncthreads();
  }

#pragma unroll
  for (int i = 0; i < 4; ++i) {
    int gr = row0 + ty * 4 + i;
    if (gr >= M) continue;
#pragma unroll
    for (int j = 0; j < 4; ++j) {
      int gc = col0 + tx * 4 + j;
      float v = acc[i][j];
      if (EPI) {
        v += bias[gc];
        v = fmaxf(v, 0.0f);
        unsigned jj = (unsigned)gr * (unsigned)N + (unsigned)gc;
        v *= drop_scale(jj, dk0, dk1);
      }
      C[(size_t)gr * N + gc] = v;
    }
  }
}

// ---------------- final epilogue: out = drop(relu(agg + b2)) in place -------
__global__ __launch_bounds__(256) void k_final(float* __restrict__ buf,
                                               const float* __restrict__ bias,
                                               int total,
                                               unsigned dk0, unsigned dk1) {
  int j = blockIdx.x * 256 + threadIdx.x;
  if (j >= total) return;
  float v = buf[j] + bias[j & (C_OUT - 1)];
  v = fmaxf(v, 0.0f);
  buf[j] = v * drop_scale((unsigned)j, dk0, dk1);
}

extern "C" void kernel_launch(void* const* d_in, const int* in_sizes, int n_in,
                              void* d_out, int out_size, void* d_ws, size_t ws_size,
                              hipStream_t stream) {
  const float* x  = (const float*)d_in[0];
  const void*  ei = d_in[1];
  const float* W1 = (const float*)d_in[2];
  const float* b1 = (const float*)d_in[3];
  const float* W2 = (const float*)d_in[4];
  const float* b2 = (const float*)d_in[5];
  float* out = (float*)d_out;

  const int N = in_sizes[0] / C_IN;   // 10000
  const int E = in_sizes[1] / 2;      // 160000

  // foldlike split(key(42)): dk_i = threefry((0,42), (0, i)), full output pair
  unsigned a0 = 0u, a1 = 0u, b0 = 0u, b1k = 1u;
  tf_rounds(a0, a1, 0u, 42u);   // dk1 = (a0, a1)
  tf_rounds(b0, b1k, 0u, 42u);  // dk2 = (b0, b1k)

  // workspace layout
  uintptr_t base = (uintptr_t)d_ws;
  unsigned* flag = (unsigned*)base;                       // 4 B
  float*    dinv = (float*)(base + 1024);                 // 40 KB
  int*      eic  = (int*)(base + 65536);                  // 1.28 MB
  float*    agg1 = (float*)(base + 2u * 1024 * 1024);     // 10.24 MB
  float*    h1   = (float*)(base + 16u * 1024 * 1024);    // 20.48 MB
  float*    hw2  = agg1;  // reuse: agg1 dead after GEMM1

  dim3 b256(256);
  // edge dtype canonicalization
  k_detect<<<dim3(1), b256, 0, stream>>>((const unsigned*)ei, flag, 8192);
  k_convert<<<dim3((2 * E + 255) / 256), b256, 0, stream>>>(ei, flag, eic, 2 * E);
  // degrees
  k_deg_init<<<dim3((N + 255) / 256), b256, 0, stream>>>(dinv, N);
  k_deg_count<<<dim3((E + 255) / 256), b256, 0, stream>>>(eic, dinv, E);
  k_rsqrt<<<dim3((N + 255) / 256), b256, 0, stream>>>(dinv, N);
  // layer 1: agg1 = A_hat * X  (256 ch)
  k_self_init<<<dim3((N * 64 + 255) / 256), b256, 0, stream>>>(x, dinv, agg1, N);
  k_edge_agg<<<dim3((E + 3) / 4), b256, 0, stream>>>(eic, dinv, x, agg1, E);
  // h1 = drop(relu(agg1 @ W1 + b1))
  k_gemm<1><<<dim3(C_HID / 64, (N + 63) / 64), b256, 0, stream>>>(
      agg1, W1, b1, h1, N, C_HID, C_IN, a0, a1);
  // layer 2: hw2 = h1 @ W2  (multiply first, 256-ch aggregation)
  k_gemm<0><<<dim3(C_OUT / 64, (N + 63) / 64), b256, 0, stream>>>(
      h1, W2, nullptr, hw2, N, C_OUT, C_HID, 0u, 0u);
  // aggregate into d_out, then bias+relu+dropout in place
  k_self_init<<<dim3((N * 64 + 255) / 256), b256, 0, stream>>>(hw2, dinv, out, N);
  k_edge_agg<<<dim3((E + 3) / 4), b256, 0, stream>>>(eic, dinv, hw2, out, E);
  k_final<<<dim3((N * C_OUT + 255) / 256), b256, 0, stream>>>(
      out, b2, N * C_OUT, b0, b1k);
}

// Round 3
// 317.275 us; speedup vs baseline: 4.0713x; 4.0713x over previous
//
#include <hip/hip_runtime.h>
#include <stdint.h>

// GCN 2-layer: out = drop(relu(A_hat * (drop(relu((A_hat*X)*W1+b1)) * W2) + b2))
// A_hat applied at 256 channels in both layers (aggregate-first / multiply-first).
// Aggregation via device-built CSR (bucket by dst) + per-node gather: no fp atomics.
// Dropout: JAX threefry2x32, partitionable mode.

#define C_IN 256
#define C_HID 512
#define C_OUT 256

// ---------------- Threefry-2x32 (matches JAX) ----------------
__host__ __device__ __forceinline__ void tf_rounds(unsigned& x0, unsigned& x1,
                                                   unsigned k0, unsigned k1) {
  unsigned k2 = k0 ^ k1 ^ 0x1BD11BDAu;
#define ROT(r) { x0 += x1; x1 = (x1 << r) | (x1 >> (32 - r)); x1 ^= x0; }
  x0 += k0; x1 += k1;
  ROT(13) ROT(15) ROT(26) ROT(6)
  x0 += k1; x1 += k2 + 1u;
  ROT(17) ROT(29) ROT(16) ROT(24)
  x0 += k2; x1 += k0 + 2u;
  ROT(13) ROT(15) ROT(26) ROT(6)
  x0 += k0; x1 += k1 + 3u;
  ROT(17) ROT(29) ROT(16) ROT(24)
  x0 += k1; x1 += k2 + 4u;
  ROT(13) ROT(15) ROT(26) ROT(6)
  x0 += k2; x1 += k0 + 5u;
#undef ROT
}

// partitionable-mode dropout scale for flat element j (size < 2^32 so hi=0)
__device__ __forceinline__ float drop_scale(unsigned j, unsigned k0, unsigned k1) {
  unsigned x0 = 0u, x1 = j;
  tf_rounds(x0, x1, k0, k1);
  unsigned bits = x0 ^ x1;
  float u = __uint_as_float((bits >> 9) | 0x3f800000u) - 1.0f;
  return (u < 0.5f) ? 2.0f : 0.0f;  // keep-prob 0.5, scale 1/(1-p)=2
}

// ---------------- edge-index canonicalization ----------------
__global__ __launch_bounds__(256) void k_detect(const unsigned* __restrict__ raw,
                                                unsigned* flag, int nwords) {
  __shared__ unsigned sh[256];
  unsigned acc = 0;
  for (int i = 1 + 2 * (int)threadIdx.x; i < nwords; i += 512) acc |= raw[i];
  sh[threadIdx.x] = acc;
  __syncthreads();
  for (int s = 128; s > 0; s >>= 1) {
    if ((int)threadIdx.x < s) sh[threadIdx.x] |= sh[threadIdx.x + s];
    __syncthreads();
  }
  if (threadIdx.x == 0) *flag = (sh[0] == 0u) ? 1u : 0u;  // 1 => int64
}

__global__ __launch_bounds__(256) void k_convert(const void* __restrict__ raw,
                                                 const unsigned* __restrict__ flag,
                                                 int* __restrict__ eic, int total) {
  int i = blockIdx.x * 256 + threadIdx.x;
  if (i >= total) return;
  if (*flag) eic[i] = (int)((const long long*)raw)[i];
  else       eic[i] = ((const int*)raw)[i];
}

// ---------------- CSR build ----------------
__global__ __launch_bounds__(256) void k_zero(int* p, int n) {
  int i = blockIdx.x * 256 + threadIdx.x;
  if (i < n) p[i] = 0;
}
__global__ __launch_bounds__(256) void k_count(const int* __restrict__ eic,
                                               int* __restrict__ cnt, int E) {
  int e = blockIdx.x * 256 + threadIdx.x;
  if (e < E) atomicAdd(&cnt[eic[E + e]], 1);
}
__global__ __launch_bounds__(256) void k_dinv(const int* __restrict__ cnt,
                                              float* __restrict__ dinv, int n) {
  int i = blockIdx.x * 256 + threadIdx.x;
  if (i < n) dinv[i] = rsqrtf((float)(cnt[i] + 1));  // +1 self-loop
}
// single-block exclusive scan over n counts -> roff[0..n], cursor copy
__global__ __launch_bounds__(256) void k_scan(const int* __restrict__ cnt,
                                              int* __restrict__ roff,
                                              int* __restrict__ cursor, int n) {
  __shared__ int sh[256];
  __shared__ int carryS;
  if (threadIdx.x == 0) carryS = 0;
  __syncthreads();
  for (int base = 0; base < n; base += 256) {
    int i = base + (int)threadIdx.x;
    int v = (i < n) ? cnt[i] : 0;
    sh[threadIdx.x] = v;
    __syncthreads();
    for (int s = 1; s < 256; s <<= 1) {
      int t = ((int)threadIdx.x >= s) ? sh[threadIdx.x - s] : 0;
      __syncthreads();
      sh[threadIdx.x] += t;
      __syncthreads();
    }
    int excl = carryS + sh[threadIdx.x] - v;
    if (i < n) { roff[i] = excl; cursor[i] = excl; }
    __syncthreads();
    if (threadIdx.x == 255) carryS += sh[255];
    __syncthreads();
  }
  if (threadIdx.x == 0) roff[n] = carryS;
}
__global__ __launch_bounds__(256) void k_scatter(const int* __restrict__ eic,
                                                 int* __restrict__ cursor,
                                                 int* __restrict__ csr, int E) {
  int e = blockIdx.x * 256 + threadIdx.x;
  if (e >= E) return;
  int s = eic[e], d = eic[E + e];
  int slot = atomicAdd(&cursor[d], 1);
  csr[slot] = s;
}

// ---------------- aggregation gather: one block per node, thread = channel ----
// out[d] = dinv[d] * (dinv[d]*x[d] + sum_e dinv[src_e]*x[src_e])  [+ epilogue]
template <int EPI>
__global__ __launch_bounds__(256) void k_gather(const int* __restrict__ roff,
                                                const int* __restrict__ csr,
                                                const float* __restrict__ dinv,
                                                const float* __restrict__ x,
                                                const float* __restrict__ bias,
                                                float* __restrict__ out,
                                                unsigned dk0, unsigned dk1) {
  int node = blockIdx.x;
  int ch = threadIdx.x;
  float dd = dinv[node];
  int p = roff[node], end = roff[node + 1];
  float acc = dd * x[(size_t)node * 256 + ch];  // self-loop partial
  for (; p + 2 <= end; p += 2) {                // unroll-2 for outstanding loads
    int s0 = csr[p], s1 = csr[p + 1];
    float w0 = dinv[s0], w1 = dinv[s1];
    float v0 = x[(size_t)s0 * 256 + ch];
    float v1 = x[(size_t)s1 * 256 + ch];
    acc += w0 * v0 + w1 * v1;
  }
  if (p < end) {
    int s0 = csr[p];
    acc += dinv[s0] * x[(size_t)s0 * 256 + ch];
  }
  acc *= dd;
  if (EPI) {
    acc += bias[ch];
    acc = fmaxf(acc, 0.0f);
    unsigned j = (unsigned)node * 256u + (unsigned)ch;
    acc *= drop_scale(j, dk0, dk1);
  }
  out[(size_t)node * 256 + ch] = acc;
}

// ---------------- GEMM: C[M,N] = A[M,K] @ B[K,N], optional bias+relu+dropout ----
template <int EPI>
__global__ __launch_bounds__(256) void k_gemm(const float* __restrict__ A,
                                              const float* __restrict__ B,
                                              const float* __restrict__ bias,
                                              float* __restrict__ C,
                                              int M, int N, int K,
                                              unsigned dk0, unsigned dk1) {
  __shared__ float As[16][68];
  __shared__ float Bs[16][64];
  const int t = threadIdx.x;
  const int tx = t & 15, ty = t >> 4;
  const int row0 = blockIdx.y * 64, col0 = blockIdx.x * 64;
  float acc[4][4] = {};

  for (int kt = 0; kt < K; kt += 16) {
#pragma unroll
    for (int p = 0; p < 4; ++p) {
      int r = (t >> 4) + p * 16;
      int k = t & 15;
      int gr = row0 + r;
      As[k][r] = (gr < M) ? A[(size_t)gr * K + kt + k] : 0.0f;
    }
#pragma unroll
    for (int p = 0; p < 4; ++p) {
      int kr = (t >> 6) + p * 4;
      int c = t & 63;
      Bs[kr][c] = B[(size_t)(kt + kr) * N + col0 + c];
    }
    __syncthreads();
#pragma unroll
    for (int kk = 0; kk < 16; ++kk) {
      float4 av = *(const float4*)&As[kk][ty * 4];
      float4 bv = *(const float4*)&Bs[kk][tx * 4];
      float a[4] = {av.x, av.y, av.z, av.w};
      float b[4] = {bv.x, bv.y, bv.z, bv.w};
#pragma unroll
      for (int i = 0; i < 4; ++i)
#pragma unroll
        for (int j = 0; j < 4; ++j)
          acc[i][j] = fmaf(a[i], b[j], acc[i][j]);
    }
    __syncthreads();
  }

#pragma unroll
  for (int i = 0; i < 4; ++i) {
    int gr = row0 + ty * 4 + i;
    if (gr >= M) continue;
#pragma unroll
    for (int j = 0; j < 4; ++j) {
      int gc = col0 + tx * 4 + j;
      float v = acc[i][j];
      if (EPI) {
        v += bias[gc];
        v = fmaxf(v, 0.0f);
        unsigned jj = (unsigned)gr * (unsigned)N + (unsigned)gc;
        v *= drop_scale(jj, dk0, dk1);
      }
      C[(size_t)gr * N + gc] = v;
    }
  }
}

extern "C" void kernel_launch(void* const* d_in, const int* in_sizes, int n_in,
                              void* d_out, int out_size, void* d_ws, size_t ws_size,
                              hipStream_t stream) {
  const float* x  = (const float*)d_in[0];
  const void*  ei = d_in[1];
  const float* W1 = (const float*)d_in[2];
  const float* b1 = (const float*)d_in[3];
  const float* W2 = (const float*)d_in[4];
  const float* b2 = (const float*)d_in[5];
  float* out = (float*)d_out;

  const int N = in_sizes[0] / C_IN;   // 10000
  const int E = in_sizes[1] / 2;      // 160000

  // foldlike split(key(42)): dk_i = threefry((0,42), (0, i)), full output pair
  unsigned a0 = 0u, a1 = 0u, b0 = 0u, b1k = 1u;
  tf_rounds(a0, a1, 0u, 42u);   // dk1 = (a0, a1)
  tf_rounds(b0, b1k, 0u, 42u);  // dk2 = (b0, b1k)

  // workspace layout
  uintptr_t base = (uintptr_t)d_ws;
  unsigned* flag   = (unsigned*)base;                     // 4 B
  int*      cnt    = (int*)(base + 1024);                 // 40 KB
  int*      roff   = (int*)(base + 64 * 1024);            // 40 KB (+1)
  int*      cursor = (int*)(base + 128 * 1024);           // 40 KB
  float*    dinv   = (float*)(base + 192 * 1024);         // 40 KB
  int*      eic    = (int*)(base + 256 * 1024);           // 1.28 MB
  int*      csr    = (int*)(base + 2u * 1024 * 1024);     // 640 KB
  float*    agg1   = (float*)(base + 4u * 1024 * 1024);   // 10.24 MB
  float*    h1     = (float*)(base + 16u * 1024 * 1024);  // 20.48 MB
  float*    hw2    = agg1;  // reuse: agg1 dead after GEMM1

  dim3 b256(256);
  // edge dtype canonicalization
  k_detect<<<dim3(1), b256, 0, stream>>>((const unsigned*)ei, flag, 8192);
  k_convert<<<dim3((2 * E + 255) / 256), b256, 0, stream>>>(ei, flag, eic, 2 * E);
  // CSR build (bucket by dst)
  k_zero<<<dim3((N + 255) / 256), b256, 0, stream>>>(cnt, N);
  k_count<<<dim3((E + 255) / 256), b256, 0, stream>>>(eic, cnt, E);
  k_dinv<<<dim3((N + 255) / 256), b256, 0, stream>>>(cnt, dinv, N);
  k_scan<<<dim3(1), b256, 0, stream>>>(cnt, roff, cursor, N);
  k_scatter<<<dim3((E + 255) / 256), b256, 0, stream>>>(eic, cursor, csr, E);
  // layer 1: agg1 = A_hat * X  (gather, no atomics)
  k_gather<0><<<dim3(N), b256, 0, stream>>>(roff, csr, dinv, x, nullptr, agg1, 0u, 0u);
  // h1 = drop(relu(agg1 @ W1 + b1))
  k_gemm<1><<<dim3(C_HID / 64, (N + 63) / 64), b256, 0, stream>>>(
      agg1, W1, b1, h1, N, C_HID, C_IN, a0, a1);
  // layer 2: hw2 = h1 @ W2  (multiply first)
  k_gemm<0><<<dim3(C_OUT / 64, (N + 63) / 64), b256, 0, stream>>>(
      h1, W2, nullptr, hw2, N, C_OUT, C_HID, 0u, 0u);
  // out = drop(relu(A_hat * hw2 + b2))  (gather with fused epilogue)
  k_gather<1><<<dim3(N), b256, 0, stream>>>(roff, csr, dinv, hw2, b2, out, b0, b1k);
}

// Round 4
// 260.513 us; speedup vs baseline: 4.9584x; 1.2179x over previous
//
#include <hip/hip_runtime.h>
#include <stdint.h>

// GCN 2-layer: out = drop(relu(A_hat * (drop(relu((A_hat*X)*W1+b1)) * W2) + b2))
// - A_hat applied at 256 ch both layers (aggregate-first / multiply-first)
// - CSR gather aggregation (no fp atomics)
// - GEMMs: bf16x3 split MFMA (hi*hi + hi*lo + lo*hi), 128x128 tiles, mfma_f32_16x16x32_bf16
// - Dropout: JAX threefry2x32, partitionable mode

#define C_IN 256
#define C_HID 512
#define C_OUT 256

typedef unsigned short ushort_t;
typedef __bf16 bf16x8 __attribute__((ext_vector_type(8)));
typedef float floatx4 __attribute__((ext_vector_type(4)));

// ---------------- Threefry-2x32 (matches JAX) ----------------
__host__ __device__ __forceinline__ void tf_rounds(unsigned& x0, unsigned& x1,
                                                   unsigned k0, unsigned k1) {
  unsigned k2 = k0 ^ k1 ^ 0x1BD11BDAu;
#define ROT(r) { x0 += x1; x1 = (x1 << r) | (x1 >> (32 - r)); x1 ^= x0; }
  x0 += k0; x1 += k1;
  ROT(13) ROT(15) ROT(26) ROT(6)
  x0 += k1; x1 += k2 + 1u;
  ROT(17) ROT(29) ROT(16) ROT(24)
  x0 += k2; x1 += k0 + 2u;
  ROT(13) ROT(15) ROT(26) ROT(6)
  x0 += k0; x1 += k1 + 3u;
  ROT(17) ROT(29) ROT(16) ROT(24)
  x0 += k1; x1 += k2 + 4u;
  ROT(13) ROT(15) ROT(26) ROT(6)
  x0 += k2; x1 += k0 + 5u;
#undef ROT
}

__device__ __forceinline__ float drop_scale(unsigned j, unsigned k0, unsigned k1) {
  unsigned x0 = 0u, x1 = j;
  tf_rounds(x0, x1, k0, k1);
  unsigned bits = x0 ^ x1;
  float u = __uint_as_float((bits >> 9) | 0x3f800000u) - 1.0f;
  return (u < 0.5f) ? 2.0f : 0.0f;
}

// bf16 helpers (RNE)
__device__ __forceinline__ ushort_t f2bf(float f) {
  unsigned u = __float_as_uint(f);
  unsigned r = (u + 0x7fffu + ((u >> 16) & 1u)) >> 16;
  return (ushort_t)r;
}
__device__ __forceinline__ float bf2f(ushort_t h) {
  return __uint_as_float(((unsigned)h) << 16);
}

// ---------------- edge-index canonicalization ----------------
__global__ __launch_bounds__(256) void k_detect(const unsigned* __restrict__ raw,
                                                unsigned* flag, int nwords) {
  __shared__ unsigned sh[256];
  unsigned acc = 0;
  for (int i = 1 + 2 * (int)threadIdx.x; i < nwords; i += 512) acc |= raw[i];
  sh[threadIdx.x] = acc;
  __syncthreads();
  for (int s = 128; s > 0; s >>= 1) {
    if ((int)threadIdx.x < s) sh[threadIdx.x] |= sh[threadIdx.x + s];
    __syncthreads();
  }
  if (threadIdx.x == 0) *flag = (sh[0] == 0u) ? 1u : 0u;  // 1 => int64
}

__global__ __launch_bounds__(256) void k_convert(const void* __restrict__ raw,
                                                 const unsigned* __restrict__ flag,
                                                 int* __restrict__ eic, int total) {
  int i = blockIdx.x * 256 + threadIdx.x;
  if (i >= total) return;
  if (*flag) eic[i] = (int)((const long long*)raw)[i];
  else       eic[i] = ((const int*)raw)[i];
}

// ---------------- CSR build ----------------
__global__ __launch_bounds__(256) void k_zero(int* p, int n) {
  int i = blockIdx.x * 256 + threadIdx.x;
  if (i < n) p[i] = 0;
}
__global__ __launch_bounds__(256) void k_count(const int* __restrict__ eic,
                                               int* __restrict__ cnt, int E) {
  int e = blockIdx.x * 256 + threadIdx.x;
  if (e < E) atomicAdd(&cnt[eic[E + e]], 1);
}
__global__ __launch_bounds__(256) void k_dinv(const int* __restrict__ cnt,
                                              float* __restrict__ dinv, int n) {
  int i = blockIdx.x * 256 + threadIdx.x;
  if (i < n) dinv[i] = rsqrtf((float)(cnt[i] + 1));
}
__global__ __launch_bounds__(256) void k_scan(const int* __restrict__ cnt,
                                              int* __restrict__ roff,
                                              int* __restrict__ cursor, int n) {
  __shared__ int sh[256];
  __shared__ int carryS;
  if (threadIdx.x == 0) carryS = 0;
  __syncthreads();
  for (int base = 0; base < n; base += 256) {
    int i = base + (int)threadIdx.x;
    int v = (i < n) ? cnt[i] : 0;
    sh[threadIdx.x] = v;
    __syncthreads();
    for (int s = 1; s < 256; s <<= 1) {
      int t = ((int)threadIdx.x >= s) ? sh[threadIdx.x - s] : 0;
      __syncthreads();
      sh[threadIdx.x] += t;
      __syncthreads();
    }
    int excl = carryS + sh[threadIdx.x] - v;
    if (i < n) { roff[i] = excl; cursor[i] = excl; }
    __syncthreads();
    if (threadIdx.x == 255) carryS += sh[255];
    __syncthreads();
  }
  if (threadIdx.x == 0) roff[n] = carryS;
}
__global__ __launch_bounds__(256) void k_scatter(const int* __restrict__ eic,
                                                 int* __restrict__ cursor,
                                                 int* __restrict__ csr, int E) {
  int e = blockIdx.x * 256 + threadIdx.x;
  if (e >= E) return;
  int s = eic[e], d = eic[E + e];
  int slot = atomicAdd(&cursor[d], 1);
  csr[slot] = s;
}

// ---------------- weight convert + transpose: W[K][N] -> Wt hi/lo [N][K] ----
__global__ __launch_bounds__(256) void k_wconv(const float* __restrict__ W,
                                               ushort_t* __restrict__ hi,
                                               ushort_t* __restrict__ lo,
                                               int K, int N) {
  int idx = blockIdx.x * 256 + threadIdx.x;
  if (idx >= K * N) return;
  int k = idx / N, n = idx - k * N;
  float v = W[idx];
  ushort_t h = f2bf(v);
  float r = v - bf2f(h);
  hi[(size_t)n * K + k] = h;
  lo[(size_t)n * K + k] = f2bf(r);
}

// ---------------- gather: 4 nodes/block, 64 lanes x float4 per node ---------
// EPI=0: write bf16 split (Ahi/Alo). EPI=1: write fp32 out with bias+relu+drop.
template <int EPI>
__global__ __launch_bounds__(256) void k_gather4(const int* __restrict__ roff,
                                                 const int* __restrict__ csr,
                                                 const float* __restrict__ dinv,
                                                 const float* __restrict__ x,
                                                 const float* __restrict__ bias,
                                                 void* __restrict__ o1,
                                                 void* __restrict__ o2,
                                                 unsigned dk0, unsigned dk1) {
  int g = threadIdx.x >> 6;
  int tg = threadIdx.x & 63;
  int node = blockIdx.x * 4 + g;
  float dd = dinv[node];
  float4 v = ((const float4*)(x + (size_t)node * 256))[tg];
  float4 acc = make_float4(dd * v.x, dd * v.y, dd * v.z, dd * v.w);
  int p = roff[node], end = roff[node + 1];
  for (; p + 2 <= end; p += 2) {
    int s0 = csr[p], s1 = csr[p + 1];
    float w0 = dinv[s0], w1 = dinv[s1];
    float4 a = ((const float4*)(x + (size_t)s0 * 256))[tg];
    float4 b = ((const float4*)(x + (size_t)s1 * 256))[tg];
    acc.x += w0 * a.x + w1 * b.x;
    acc.y += w0 * a.y + w1 * b.y;
    acc.z += w0 * a.z + w1 * b.z;
    acc.w += w0 * a.w + w1 * b.w;
  }
  if (p < end) {
    int s0 = csr[p];
    float w0 = dinv[s0];
    float4 a = ((const float4*)(x + (size_t)s0 * 256))[tg];
    acc.x += w0 * a.x; acc.y += w0 * a.y; acc.z += w0 * a.z; acc.w += w0 * a.w;
  }
  acc.x *= dd; acc.y *= dd; acc.z *= dd; acc.w *= dd;
  if (EPI) {
    float4 bb = ((const float4*)bias)[tg];
    acc.x = fmaxf(acc.x + bb.x, 0.0f);
    acc.y = fmaxf(acc.y + bb.y, 0.0f);
    acc.z = fmaxf(acc.z + bb.z, 0.0f);
    acc.w = fmaxf(acc.w + bb.w, 0.0f);
    unsigned jb = (unsigned)node * 256u + (unsigned)tg * 4u;
    acc.x *= drop_scale(jb + 0u, dk0, dk1);
    acc.y *= drop_scale(jb + 1u, dk0, dk1);
    acc.z *= drop_scale(jb + 2u, dk0, dk1);
    acc.w *= drop_scale(jb + 3u, dk0, dk1);
    ((float4*)o1)[(size_t)node * 64 + tg] = acc;
  } else {
    ushort_t h0 = f2bf(acc.x), h1 = f2bf(acc.y), h2 = f2bf(acc.z), h3 = f2bf(acc.w);
    ushort4 hv = make_ushort4(h0, h1, h2, h3);
    ushort4 lv = make_ushort4(f2bf(acc.x - bf2f(h0)), f2bf(acc.y - bf2f(h1)),
                              f2bf(acc.z - bf2f(h2)), f2bf(acc.w - bf2f(h3)));
    ((ushort4*)o1)[(size_t)node * 64 + tg] = hv;
    ((ushort4*)o2)[(size_t)node * 64 + tg] = lv;
  }
}

// ---------------- bf16x3 MFMA GEMM: C[M,N] = (Ahi+Alo) @ (Bhi+Blo)^T' -------
// A: [M][K] bf16 hi/lo, B: [N][K] bf16 hi/lo (pre-transposed weights).
// 128x128 tile, BK=32, 4 waves (2x2), 4x4 frags of mfma_f32_16x16x32_bf16.
template <int EPI>
__global__ __launch_bounds__(256) void k_gemm3(
    const ushort_t* __restrict__ Ahi, const ushort_t* __restrict__ Alo,
    const ushort_t* __restrict__ Bhi, const ushort_t* __restrict__ Blo,
    const float* __restrict__ bias,
    ushort_t* __restrict__ Chi, ushort_t* __restrict__ Clo,  // EPI=1 outputs
    float* __restrict__ Cf,                                  // EPI=0 output
    int M, int N, int K, unsigned dk0, unsigned dk1) {
  __shared__ ushort_t sAh[128 * 32], sAl[128 * 32], sBh[128 * 32], sBl[128 * 32];
  const int t = threadIdx.x;
  const int lane = t & 63, wave = t >> 6;
  const int wm = wave & 1, wn = wave >> 1;
  const int quad = lane >> 4, l16 = lane & 15;
  const int row0 = blockIdx.y * 128, col0 = blockIdx.x * 128;
  const int srow = t >> 2;          // 0..63 (and +64 for second chunk)
  const int skc = (t & 3) * 8;      // k element offset (8 bf16 = 16B)

  floatx4 acc[4][4] = {};

  const int ra0 = min(row0 + srow, M - 1);
  const int ra1 = min(row0 + 64 + srow, M - 1);
  const int rb0 = col0 + srow;
  const int rb1 = col0 + 64 + srow;

  for (int kt = 0; kt < K; kt += 32) {
    const size_t ka = (size_t)kt + skc;
    uint4 vA0h = *(const uint4*)(Ahi + (size_t)ra0 * K + ka);
    uint4 vA1h = *(const uint4*)(Ahi + (size_t)ra1 * K + ka);
    uint4 vA0l = *(const uint4*)(Alo + (size_t)ra0 * K + ka);
    uint4 vA1l = *(const uint4*)(Alo + (size_t)ra1 * K + ka);
    uint4 vB0h = *(const uint4*)(Bhi + (size_t)rb0 * K + ka);
    uint4 vB1h = *(const uint4*)(Bhi + (size_t)rb1 * K + ka);
    uint4 vB0l = *(const uint4*)(Blo + (size_t)rb0 * K + ka);
    uint4 vB1l = *(const uint4*)(Blo + (size_t)rb1 * K + ka);
    __syncthreads();  // prior iteration's LDS reads complete
    *(uint4*)&sAh[srow * 32 + skc] = vA0h;
    *(uint4*)&sAh[(64 + srow) * 32 + skc] = vA1h;
    *(uint4*)&sAl[srow * 32 + skc] = vA0l;
    *(uint4*)&sAl[(64 + srow) * 32 + skc] = vA1l;
    *(uint4*)&sBh[srow * 32 + skc] = vB0h;
    *(uint4*)&sBh[(64 + srow) * 32 + skc] = vB1h;
    *(uint4*)&sBl[srow * 32 + skc] = vB0l;
    *(uint4*)&sBl[(64 + srow) * 32 + skc] = vB1l;
    __syncthreads();

    bf16x8 ah[4], al[4], bh[4], bl[4];
#pragma unroll
    for (int i = 0; i < 4; ++i) {
      int off = (wm * 64 + i * 16 + l16) * 32 + quad * 8;
      ah[i] = *(const bf16x8*)&sAh[off];
      al[i] = *(const bf16x8*)&sAl[off];
    }
#pragma unroll
    for (int j = 0; j < 4; ++j) {
      int off = (wn * 64 + j * 16 + l16) * 32 + quad * 8;
      bh[j] = *(const bf16x8*)&sBh[off];
      bl[j] = *(const bf16x8*)&sBl[off];
    }
#pragma unroll
    for (int i = 0; i < 4; ++i)
#pragma unroll
      for (int j = 0; j < 4; ++j) {
        acc[i][j] = __builtin_amdgcn_mfma_f32_16x16x32_bf16(ah[i], bh[j], acc[i][j], 0, 0, 0);
        acc[i][j] = __builtin_amdgcn_mfma_f32_16x16x32_bf16(ah[i], bl[j], acc[i][j], 0, 0, 0);
        acc[i][j] = __builtin_amdgcn_mfma_f32_16x16x32_bf16(al[i], bh[j], acc[i][j], 0, 0, 0);
      }
  }

#pragma unroll
  for (int i = 0; i < 4; ++i) {
#pragma unroll
    for (int j = 0; j < 4; ++j) {
      int gc = col0 + wn * 64 + j * 16 + l16;
#pragma unroll
      for (int reg = 0; reg < 4; ++reg) {
        int gr = row0 + wm * 64 + i * 16 + quad * 4 + reg;
        if (gr >= M) continue;
        float v = acc[i][j][reg];
        size_t o = (size_t)gr * N + gc;
        if (EPI) {
          v += bias[gc];
          v = fmaxf(v, 0.0f);
          v *= drop_scale((unsigned)gr * (unsigned)N + (unsigned)gc, dk0, dk1);
          ushort_t h = f2bf(v);
          Chi[o] = h;
          Clo[o] = f2bf(v - bf2f(h));
        } else {
          Cf[o] = v;
        }
      }
    }
  }
}

extern "C" void kernel_launch(void* const* d_in, const int* in_sizes, int n_in,
                              void* d_out, int out_size, void* d_ws, size_t ws_size,
                              hipStream_t stream) {
  const float* x  = (const float*)d_in[0];
  const void*  ei = d_in[1];
  const float* W1 = (const float*)d_in[2];
  const float* b1 = (const float*)d_in[3];
  const float* W2 = (const float*)d_in[4];
  const float* b2 = (const float*)d_in[5];
  float* out = (float*)d_out;

  const int N = in_sizes[0] / C_IN;   // 10000
  const int E = in_sizes[1] / 2;      // 160000

  // foldlike split(key(42)): dk_i = threefry((0,42), (0, i))
  unsigned a0 = 0u, a1 = 0u, b0 = 0u, b1k = 1u;
  tf_rounds(a0, a1, 0u, 42u);   // dk1
  tf_rounds(b0, b1k, 0u, 42u);  // dk2

  // workspace layout
  uintptr_t base = (uintptr_t)d_ws;
  unsigned*  flag   = (unsigned*)base;
  int*       cnt    = (int*)(base + 1024);
  int*       roff   = (int*)(base + 64 * 1024);
  int*       cursor = (int*)(base + 128 * 1024);
  float*     dinv   = (float*)(base + 192 * 1024);
  int*       eic    = (int*)(base + 256 * 1024);              // 1.28 MB
  int*       csr    = (int*)(base + 2u * 1024 * 1024);        // 640 KB
  ushort_t*  Ahi    = (ushort_t*)(base + 4u  * 1024 * 1024);  // 5.12 MB
  ushort_t*  Alo    = (ushort_t*)(base + 10u * 1024 * 1024);  // 5.12 MB
  ushort_t*  H1hi   = (ushort_t*)(base + 16u * 1024 * 1024);  // 10.24 MB
  ushort_t*  H1lo   = (ushort_t*)(base + 27u * 1024 * 1024);  // 10.24 MB
  float*     hw2    = (float*)(base + 38u * 1024 * 1024);     // 10.24 MB
  ushort_t*  W1thi  = (ushort_t*)(base + 49u * 1024 * 1024);  // 256 KB
  ushort_t*  W1tlo  = (ushort_t*)(base + 49u * 1024 * 1024 + 512 * 1024);
  ushort_t*  W2thi  = (ushort_t*)(base + 50u * 1024 * 1024);
  ushort_t*  W2tlo  = (ushort_t*)(base + 50u * 1024 * 1024 + 512 * 1024);

  dim3 b256(256);
  k_detect<<<dim3(1), b256, 0, stream>>>((const unsigned*)ei, flag, 8192);
  k_convert<<<dim3((2 * E + 255) / 256), b256, 0, stream>>>(ei, flag, eic, 2 * E);
  k_zero<<<dim3((N + 255) / 256), b256, 0, stream>>>(cnt, N);
  k_count<<<dim3((E + 255) / 256), b256, 0, stream>>>(eic, cnt, E);
  k_dinv<<<dim3((N + 255) / 256), b256, 0, stream>>>(cnt, dinv, N);
  k_scan<<<dim3(1), b256, 0, stream>>>(cnt, roff, cursor, N);
  k_scatter<<<dim3((E + 255) / 256), b256, 0, stream>>>(eic, cursor, csr, E);
  // weights -> bf16 split, transposed [N][K]
  k_wconv<<<dim3((C_IN * C_HID + 255) / 256), b256, 0, stream>>>(W1, W1thi, W1tlo, C_IN, C_HID);
  k_wconv<<<dim3((C_HID * C_OUT + 255) / 256), b256, 0, stream>>>(W2, W2thi, W2tlo, C_HID, C_OUT);
  // layer 1 aggregate (gather) -> bf16 split A
  k_gather4<0><<<dim3(N / 4), b256, 0, stream>>>(roff, csr, dinv, x, nullptr,
                                                 Ahi, Alo, 0u, 0u);
  // h1 = drop(relu(agg @ W1 + b1)) -> bf16 split
  k_gemm3<1><<<dim3(C_HID / 128, (N + 127) / 128), b256, 0, stream>>>(
      Ahi, Alo, W1thi, W1tlo, b1, H1hi, H1lo, nullptr, N, C_HID, C_IN, a0, a1);
  // hw2 = h1 @ W2 (fp32 out)
  k_gemm3<0><<<dim3(C_OUT / 128, (N + 127) / 128), b256, 0, stream>>>(
      H1hi, H1lo, W2thi, W2tlo, nullptr, nullptr, nullptr, hw2, N, C_OUT, C_HID, 0u, 0u);
  // out = drop(relu(A_hat * hw2 + b2))
  k_gather4<1><<<dim3(N / 4), b256, 0, stream>>>(roff, csr, dinv, hw2, b2,
                                                 out, nullptr, b0, b1k);
}

// Round 5
// 215.787 us; speedup vs baseline: 5.9861x; 1.2073x over previous
//
#include <hip/hip_runtime.h>
#include <stdint.h>

// GCN 2-layer: out = drop(relu(A_hat * (drop(relu((A_hat*X)*W1+b1)) * W2) + b2))
// - A_hat applied at 256 ch both layers (aggregate-first / multiply-first)
// - CSR gather aggregation (no fp atomics); hierarchical 3-phase scan
// - GEMMs: bf16x3 split MFMA (hi*hi + hi*lo + lo*hi), 128x128 tiles, mfma_f32_16x16x32_bf16
// - Dropout: JAX threefry2x32, partitionable mode

#define C_IN 256
#define C_HID 512
#define C_OUT 256

typedef unsigned short ushort_t;
typedef __bf16 bf16x8 __attribute__((ext_vector_type(8)));
typedef float floatx4 __attribute__((ext_vector_type(4)));

// ---------------- Threefry-2x32 (matches JAX) ----------------
__host__ __device__ __forceinline__ void tf_rounds(unsigned& x0, unsigned& x1,
                                                   unsigned k0, unsigned k1) {
  unsigned k2 = k0 ^ k1 ^ 0x1BD11BDAu;
#define ROT(r) { x0 += x1; x1 = (x1 << r) | (x1 >> (32 - r)); x1 ^= x0; }
  x0 += k0; x1 += k1;
  ROT(13) ROT(15) ROT(26) ROT(6)
  x0 += k1; x1 += k2 + 1u;
  ROT(17) ROT(29) ROT(16) ROT(24)
  x0 += k2; x1 += k0 + 2u;
  ROT(13) ROT(15) ROT(26) ROT(6)
  x0 += k0; x1 += k1 + 3u;
  ROT(17) ROT(29) ROT(16) ROT(24)
  x0 += k1; x1 += k2 + 4u;
  ROT(13) ROT(15) ROT(26) ROT(6)
  x0 += k2; x1 += k0 + 5u;
#undef ROT
}

__device__ __forceinline__ float drop_scale(unsigned j, unsigned k0, unsigned k1) {
  unsigned x0 = 0u, x1 = j;
  tf_rounds(x0, x1, k0, k1);
  unsigned bits = x0 ^ x1;
  float u = __uint_as_float((bits >> 9) | 0x3f800000u) - 1.0f;
  return (u < 0.5f) ? 2.0f : 0.0f;
}

// bf16 helpers (RNE)
__device__ __forceinline__ ushort_t f2bf(float f) {
  unsigned u = __float_as_uint(f);
  unsigned r = (u + 0x7fffu + ((u >> 16) & 1u)) >> 16;
  return (ushort_t)r;
}
__device__ __forceinline__ float bf2f(ushort_t h) {
  return __uint_as_float(((unsigned)h) << 16);
}

// ---------------- edge-index canonicalization ----------------
__global__ __launch_bounds__(256) void k_detect(const unsigned* __restrict__ raw,
                                                unsigned* flag, int nwords) {
  __shared__ unsigned sh[256];
  unsigned acc = 0;
  for (int i = 1 + 2 * (int)threadIdx.x; i < nwords; i += 512) acc |= raw[i];
  sh[threadIdx.x] = acc;
  __syncthreads();
  for (int s = 128; s > 0; s >>= 1) {
    if ((int)threadIdx.x < s) sh[threadIdx.x] |= sh[threadIdx.x + s];
    __syncthreads();
  }
  if (threadIdx.x == 0) *flag = (sh[0] == 0u) ? 1u : 0u;  // 1 => int64
}

__global__ __launch_bounds__(256) void k_zero(int* p, int n) {
  int i = blockIdx.x * 256 + threadIdx.x;
  if (i < n) p[i] = 0;
}

// convert + fused dst-degree histogram (cnt must be pre-zeroed)
__global__ __launch_bounds__(256) void k_convert(const void* __restrict__ raw,
                                                 const unsigned* __restrict__ flag,
                                                 int* __restrict__ eic,
                                                 int* __restrict__ cnt,
                                                 int E) {
  int i = blockIdx.x * 256 + threadIdx.x;
  if (i >= 2 * E) return;
  int v;
  if (*flag) v = (int)((const long long*)raw)[i];
  else       v = ((const int*)raw)[i];
  eic[i] = v;
  if (i >= E) atomicAdd(&cnt[v], 1);  // dst half -> in-degree
}

// ---------------- hierarchical scan: A (block sums), B (scan sums), C (emit) --
__global__ __launch_bounds__(256) void k_scan_a(const int* __restrict__ cnt,
                                                int* __restrict__ bsum, int n) {
  __shared__ int sh[256];
  int i = blockIdx.x * 256 + threadIdx.x;
  sh[threadIdx.x] = (i < n) ? cnt[i] : 0;
  __syncthreads();
  for (int s = 128; s > 0; s >>= 1) {
    if ((int)threadIdx.x < s) sh[threadIdx.x] += sh[threadIdx.x + s];
    __syncthreads();
  }
  if (threadIdx.x == 0) bsum[blockIdx.x] = sh[0];
}
__global__ __launch_bounds__(64) void k_scan_b(const int* __restrict__ bsum,
                                               int* __restrict__ boff,
                                               int* __restrict__ roff_last,
                                               int nb) {
  if (threadIdx.x == 0) {
    int run = 0;
    for (int b = 0; b < nb; ++b) { boff[b] = run; run += bsum[b]; }
    *roff_last = run;
  }
}
// phase C: in-block scan + block offset -> roff/cursor; fused dinv
__global__ __launch_bounds__(256) void k_scan_c(const int* __restrict__ cnt,
                                                const int* __restrict__ boff,
                                                int* __restrict__ roff,
                                                int* __restrict__ cursor,
                                                float* __restrict__ dinv, int n) {
  __shared__ int sh[256];
  int i = blockIdx.x * 256 + threadIdx.x;
  int v = (i < n) ? cnt[i] : 0;
  sh[threadIdx.x] = v;
  __syncthreads();
  for (int s = 1; s < 256; s <<= 1) {
    int t = ((int)threadIdx.x >= s) ? sh[threadIdx.x - s] : 0;
    __syncthreads();
    sh[threadIdx.x] += t;
    __syncthreads();
  }
  if (i < n) {
    int excl = boff[blockIdx.x] + sh[threadIdx.x] - v;
    roff[i] = excl;
    cursor[i] = excl;
    dinv[i] = rsqrtf((float)(v + 1));  // +1 self-loop
  }
}

__global__ __launch_bounds__(256) void k_scatter(const int* __restrict__ eic,
                                                 int* __restrict__ cursor,
                                                 int* __restrict__ csr, int E) {
  int e = blockIdx.x * 256 + threadIdx.x;
  if (e >= E) return;
  int s = eic[e], d = eic[E + e];
  int slot = atomicAdd(&cursor[d], 1);
  csr[slot] = s;
}

// ---------------- weight convert + transpose (both weights, one launch) ----
// W1[K1=256][N1=512] -> W1t hi/lo [512][256]; W2[K2=512][N2=256] -> [256][512]
__global__ __launch_bounds__(256) void k_wconv2(const float* __restrict__ W1,
                                                const float* __restrict__ W2,
                                                ushort_t* __restrict__ h1,
                                                ushort_t* __restrict__ l1,
                                                ushort_t* __restrict__ h2,
                                                ushort_t* __restrict__ l2) {
  int idx = blockIdx.x * 256 + threadIdx.x;
  const int S1 = C_IN * C_HID;
  const float* W; ushort_t *hi, *lo; int K, Nn, li;
  if (idx < S1) { W = W1; hi = h1; lo = l1; K = C_IN; Nn = C_HID; li = idx; }
  else { W = W2; hi = h2; lo = l2; K = C_HID; Nn = C_OUT; li = idx - S1; }
  int k = li / Nn, n = li - k * Nn;
  float v = W[li];
  ushort_t h = f2bf(v);
  hi[(size_t)n * K + k] = h;
  lo[(size_t)n * K + k] = f2bf(v - bf2f(h));
}

// ---------------- gather: 4 nodes/block, 64 lanes x float4, unroll-4 --------
template <int EPI>
__global__ __launch_bounds__(256) void k_gather4(const int* __restrict__ roff,
                                                 const int* __restrict__ csr,
                                                 const float* __restrict__ dinv,
                                                 const float* __restrict__ x,
                                                 const float* __restrict__ bias,
                                                 void* __restrict__ o1,
                                                 void* __restrict__ o2,
                                                 unsigned dk0, unsigned dk1) {
  int g = threadIdx.x >> 6;
  int tg = threadIdx.x & 63;
  int node = blockIdx.x * 4 + g;
  float dd = dinv[node];
  float4 v = ((const float4*)(x + (size_t)node * 256))[tg];
  float4 acc = make_float4(dd * v.x, dd * v.y, dd * v.z, dd * v.w);
  int p = roff[node], end = roff[node + 1];
  for (; p + 4 <= end; p += 4) {
    int s0 = csr[p], s1 = csr[p + 1], s2 = csr[p + 2], s3 = csr[p + 3];
    float w0 = dinv[s0], w1 = dinv[s1], w2 = dinv[s2], w3 = dinv[s3];
    float4 a = ((const float4*)(x + (size_t)s0 * 256))[tg];
    float4 b = ((const float4*)(x + (size_t)s1 * 256))[tg];
    float4 c = ((const float4*)(x + (size_t)s2 * 256))[tg];
    float4 d = ((const float4*)(x + (size_t)s3 * 256))[tg];
    acc.x += w0 * a.x + w1 * b.x + w2 * c.x + w3 * d.x;
    acc.y += w0 * a.y + w1 * b.y + w2 * c.y + w3 * d.y;
    acc.z += w0 * a.z + w1 * b.z + w2 * c.z + w3 * d.z;
    acc.w += w0 * a.w + w1 * b.w + w2 * c.w + w3 * d.w;
  }
  for (; p < end; ++p) {
    int s0 = csr[p];
    float w0 = dinv[s0];
    float4 a = ((const float4*)(x + (size_t)s0 * 256))[tg];
    acc.x += w0 * a.x; acc.y += w0 * a.y; acc.z += w0 * a.z; acc.w += w0 * a.w;
  }
  acc.x *= dd; acc.y *= dd; acc.z *= dd; acc.w *= dd;
  if (EPI) {
    float4 bb = ((const float4*)bias)[tg];
    acc.x = fmaxf(acc.x + bb.x, 0.0f);
    acc.y = fmaxf(acc.y + bb.y, 0.0f);
    acc.z = fmaxf(acc.z + bb.z, 0.0f);
    acc.w = fmaxf(acc.w + bb.w, 0.0f);
    unsigned jb = (unsigned)node * 256u + (unsigned)tg * 4u;
    acc.x *= drop_scale(jb + 0u, dk0, dk1);
    acc.y *= drop_scale(jb + 1u, dk0, dk1);
    acc.z *= drop_scale(jb + 2u, dk0, dk1);
    acc.w *= drop_scale(jb + 3u, dk0, dk1);
    ((float4*)o1)[(size_t)node * 64 + tg] = acc;
  } else {
    ushort_t h0 = f2bf(acc.x), h1 = f2bf(acc.y), h2 = f2bf(acc.z), h3 = f2bf(acc.w);
    ushort4 hv = make_ushort4(h0, h1, h2, h3);
    ushort4 lv = make_ushort4(f2bf(acc.x - bf2f(h0)), f2bf(acc.y - bf2f(h1)),
                              f2bf(acc.z - bf2f(h2)), f2bf(acc.w - bf2f(h3)));
    ((ushort4*)o1)[(size_t)node * 64 + tg] = hv;
    ((ushort4*)o2)[(size_t)node * 64 + tg] = lv;
  }
}

// ---------------- bf16x3 MFMA GEMM ----------------
template <int EPI>
__global__ __launch_bounds__(256) void k_gemm3(
    const ushort_t* __restrict__ Ahi, const ushort_t* __restrict__ Alo,
    const ushort_t* __restrict__ Bhi, const ushort_t* __restrict__ Blo,
    const float* __restrict__ bias,
    ushort_t* __restrict__ Chi, ushort_t* __restrict__ Clo,  // EPI=1 outputs
    float* __restrict__ Cf,                                  // EPI=0 output
    int M, int N, int K, unsigned dk0, unsigned dk1) {
  __shared__ ushort_t sAh[128 * 32], sAl[128 * 32], sBh[128 * 32], sBl[128 * 32];
  const int t = threadIdx.x;
  const int lane = t & 63, wave = t >> 6;
  const int wm = wave & 1, wn = wave >> 1;
  const int quad = lane >> 4, l16 = lane & 15;
  const int row0 = blockIdx.y * 128, col0 = blockIdx.x * 128;
  const int srow = t >> 2;
  const int skc = (t & 3) * 8;

  floatx4 acc[4][4] = {};

  const int ra0 = min(row0 + srow, M - 1);
  const int ra1 = min(row0 + 64 + srow, M - 1);
  const int rb0 = col0 + srow;
  const int rb1 = col0 + 64 + srow;

  for (int kt = 0; kt < K; kt += 32) {
    const size_t ka = (size_t)kt + skc;
    uint4 vA0h = *(const uint4*)(Ahi + (size_t)ra0 * K + ka);
    uint4 vA1h = *(const uint4*)(Ahi + (size_t)ra1 * K + ka);
    uint4 vA0l = *(const uint4*)(Alo + (size_t)ra0 * K + ka);
    uint4 vA1l = *(const uint4*)(Alo + (size_t)ra1 * K + ka);
    uint4 vB0h = *(const uint4*)(Bhi + (size_t)rb0 * K + ka);
    uint4 vB1h = *(const uint4*)(Bhi + (size_t)rb1 * K + ka);
    uint4 vB0l = *(const uint4*)(Blo + (size_t)rb0 * K + ka);
    uint4 vB1l = *(const uint4*)(Blo + (size_t)rb1 * K + ka);
    __syncthreads();
    *(uint4*)&sAh[srow * 32 + skc] = vA0h;
    *(uint4*)&sAh[(64 + srow) * 32 + skc] = vA1h;
    *(uint4*)&sAl[srow * 32 + skc] = vA0l;
    *(uint4*)&sAl[(64 + srow) * 32 + skc] = vA1l;
    *(uint4*)&sBh[srow * 32 + skc] = vB0h;
    *(uint4*)&sBh[(64 + srow) * 32 + skc] = vB1h;
    *(uint4*)&sBl[srow * 32 + skc] = vB0l;
    *(uint4*)&sBl[(64 + srow) * 32 + skc] = vB1l;
    __syncthreads();

    bf16x8 ah[4], al[4], bh[4], bl[4];
#pragma unroll
    for (int i = 0; i < 4; ++i) {
      int off = (wm * 64 + i * 16 + l16) * 32 + quad * 8;
      ah[i] = *(const bf16x8*)&sAh[off];
      al[i] = *(const bf16x8*)&sAl[off];
    }
#pragma unroll
    for (int j = 0; j < 4; ++j) {
      int off = (wn * 64 + j * 16 + l16) * 32 + quad * 8;
      bh[j] = *(const bf16x8*)&sBh[off];
      bl[j] = *(const bf16x8*)&sBl[off];
    }
#pragma unroll
    for (int i = 0; i < 4; ++i)
#pragma unroll
      for (int j = 0; j < 4; ++j) {
        acc[i][j] = __builtin_amdgcn_mfma_f32_16x16x32_bf16(ah[i], bh[j], acc[i][j], 0, 0, 0);
        acc[i][j] = __builtin_amdgcn_mfma_f32_16x16x32_bf16(ah[i], bl[j], acc[i][j], 0, 0, 0);
        acc[i][j] = __builtin_amdgcn_mfma_f32_16x16x32_bf16(al[i], bh[j], acc[i][j], 0, 0, 0);
      }
  }

#pragma unroll
  for (int i = 0; i < 4; ++i) {
#pragma unroll
    for (int j = 0; j < 4; ++j) {
      int gc = col0 + wn * 64 + j * 16 + l16;
#pragma unroll
      for (int reg = 0; reg < 4; ++reg) {
        int gr = row0 + wm * 64 + i * 16 + quad * 4 + reg;
        if (gr >= M) continue;
        float v = acc[i][j][reg];
        size_t o = (size_t)gr * N + gc;
        if (EPI) {
          v += bias[gc];
          v = fmaxf(v, 0.0f);
          v *= drop_scale((unsigned)gr * (unsigned)N + (unsigned)gc, dk0, dk1);
          ushort_t h = f2bf(v);
          Chi[o] = h;
          Clo[o] = f2bf(v - bf2f(h));
        } else {
          Cf[o] = v;
        }
      }
    }
  }
}

extern "C" void kernel_launch(void* const* d_in, const int* in_sizes, int n_in,
                              void* d_out, int out_size, void* d_ws, size_t ws_size,
                              hipStream_t stream) {
  const float* x  = (const float*)d_in[0];
  const void*  ei = d_in[1];
  const float* W1 = (const float*)d_in[2];
  const float* b1 = (const float*)d_in[3];
  const float* W2 = (const float*)d_in[4];
  const float* b2 = (const float*)d_in[5];
  float* out = (float*)d_out;

  const int N = in_sizes[0] / C_IN;   // 10000
  const int E = in_sizes[1] / 2;      // 160000
  const int NB = (N + 255) / 256;     // 40 scan blocks

  // foldlike split(key(42)): dk_i = threefry((0,42), (0, i))
  unsigned a0 = 0u, a1 = 0u, b0 = 0u, b1k = 1u;
  tf_rounds(a0, a1, 0u, 42u);   // dk1
  tf_rounds(b0, b1k, 0u, 42u);  // dk2

  // workspace layout
  uintptr_t base = (uintptr_t)d_ws;
  unsigned*  flag   = (unsigned*)base;
  int*       bsum   = (int*)(base + 4096);                    // 160 B
  int*       boff   = (int*)(base + 8192);                    // 160 B
  int*       cnt    = (int*)(base + 16 * 1024);               // 40 KB
  int*       roff   = (int*)(base + 64 * 1024);               // 40 KB (+1)
  int*       cursor = (int*)(base + 128 * 1024);              // 40 KB
  float*     dinv   = (float*)(base + 192 * 1024);            // 40 KB
  int*       eic    = (int*)(base + 256 * 1024);              // 1.28 MB
  int*       csr    = (int*)(base + 2u * 1024 * 1024);        // 640 KB
  ushort_t*  Ahi    = (ushort_t*)(base + 4u  * 1024 * 1024);  // 5.12 MB
  ushort_t*  Alo    = (ushort_t*)(base + 10u * 1024 * 1024);  // 5.12 MB
  ushort_t*  H1hi   = (ushort_t*)(base + 16u * 1024 * 1024);  // 10.24 MB
  ushort_t*  H1lo   = (ushort_t*)(base + 27u * 1024 * 1024);  // 10.24 MB
  float*     hw2    = (float*)(base + 38u * 1024 * 1024);     // 10.24 MB
  ushort_t*  W1thi  = (ushort_t*)(base + 49u * 1024 * 1024);  // 256 KB
  ushort_t*  W1tlo  = (ushort_t*)(base + 49u * 1024 * 1024 + 512 * 1024);
  ushort_t*  W2thi  = (ushort_t*)(base + 50u * 1024 * 1024);
  ushort_t*  W2tlo  = (ushort_t*)(base + 50u * 1024 * 1024 + 512 * 1024);

  dim3 b256(256);
  k_detect<<<dim3(1), b256, 0, stream>>>((const unsigned*)ei, flag, 8192);
  k_zero<<<dim3(NB), b256, 0, stream>>>(cnt, N);
  k_convert<<<dim3((2 * E + 255) / 256), b256, 0, stream>>>(ei, flag, eic, cnt, E);
  k_scan_a<<<dim3(NB), b256, 0, stream>>>(cnt, bsum, N);
  k_scan_b<<<dim3(1), dim3(64), 0, stream>>>(bsum, boff, roff + N, NB);
  k_scan_c<<<dim3(NB), b256, 0, stream>>>(cnt, boff, roff, cursor, dinv, N);
  k_scatter<<<dim3((E + 255) / 256), b256, 0, stream>>>(eic, cursor, csr, E);
  k_wconv2<<<dim3((C_IN * C_HID + C_HID * C_OUT + 255) / 256), b256, 0, stream>>>(
      W1, W2, W1thi, W1tlo, W2thi, W2tlo);
  // layer 1 aggregate (gather) -> bf16 split A
  k_gather4<0><<<dim3(N / 4), b256, 0, stream>>>(roff, csr, dinv, x, nullptr,
                                                 Ahi, Alo, 0u, 0u);
  // h1 = drop(relu(agg @ W1 + b1)) -> bf16 split
  k_gemm3<1><<<dim3(C_HID / 128, (N + 127) / 128), b256, 0, stream>>>(
      Ahi, Alo, W1thi, W1tlo, b1, H1hi, H1lo, nullptr, N, C_HID, C_IN, a0, a1);
  // hw2 = h1 @ W2 (fp32 out)
  k_gemm3<0><<<dim3(C_OUT / 128, (N + 127) / 128), b256, 0, stream>>>(
      H1hi, H1lo, W2thi, W2tlo, nullptr, nullptr, nullptr, hw2, N, C_OUT, C_HID, 0u, 0u);
  // out = drop(relu(A_hat * hw2 + b2))
  k_gather4<1><<<dim3(N / 4), b256, 0, stream>>>(roff, csr, dinv, hw2, b2,
                                                 out, nullptr, b0, b1k);
}